// Round 12
// baseline (182.436 us; speedup 1.0000x reference)
//
#include <hip/hip_runtime.h>
#include <hip/hip_bf16.h>
#include <math.h>

// CrossAttention: B=2, S=4096, DIM=256, NH=8, DH=32.
// R11: barrier-free GEMMs (W staged once in LDS; A-fragments per-lane direct
// from global — no per-kt barriers, loads pipeline), flash ks=4 with fp16
// partials (same partial HBM bytes as ks=2 fp32, 5 blocks/CU).
// LESSONS: SQ_LDS_BANK_CONFLICT here is inherent op-width cycles (identical
// across stride 136/152; scales with op count) — NOT a lever [R10]. LDS
// strides mult of 8 shorts [R3/R4/R6]; >=4 blocks/CU [R9]; flash K/V via
// LDS [R5]; flash inner body = R2's proven 32q shape [R8/R9].

#define SCALE 0.17677669529663687f   // 32^-0.5
#define LOG2E 1.4426950408889634f

typedef __attribute__((ext_vector_type(8))) short short8;
typedef __attribute__((ext_vector_type(8))) _Float16 half8;
typedef __attribute__((ext_vector_type(4))) float f32x4;

static __device__ __forceinline__ unsigned short f2bf(float x) {
    union { float f; unsigned int u; } v; v.f = x;
    unsigned int r = v.u + 0x7fff + ((v.u >> 16) & 1);   // RNE
    return (unsigned short)(r >> 16);
}
static __device__ __forceinline__ float fexp2(float x) {
#if __has_builtin(__builtin_amdgcn_exp2f)
    return __builtin_amdgcn_exp2f(x);
#else
    float r; asm("v_exp_f32 %0, %1" : "=v"(r) : "v"(x)); return r;
#endif
}
static __device__ __forceinline__ unsigned int pk_bf16(float a, float b) {
    unsigned int r;
    asm("v_cvt_pk_bf16_f32 %0, %1, %2" : "=v"(r) : "v"(a), "v"(b));
    return r;
}
static __device__ __forceinline__ unsigned short f2h(float x) {
    _Float16 h = (_Float16)x;
    union { _Float16 h; unsigned short s; } u; u.h = h;
    return u.s;
}
static __device__ __forceinline__ float h2f(unsigned short s) {
    union { _Float16 h; unsigned short s; } u; u.s = s;
    return (float)u.h;
}

// -------------------------------------------------- K0: W^T -> fp16 prep
__global__ __launch_bounds__(256) void prep(
    const float* __restrict__ Wq, const float* __restrict__ Wkv,
    const float* __restrict__ Wp, unsigned short* __restrict__ wfp)
{
    __shared__ float T[64][68];
    const int bb = blockIdx.x, t = threadIdx.x;
    const int mat = bb >> 4, tile = bb & 15;
    const int kr0 = (tile >> 2) * 64;
    const int nc0 = (tile & 3) * 64;
    const float* src; int ldw, cb; float sc = 1.f;
    if (mat == 0)      { src = Wq;  ldw = 256; cb = 0;   sc = SCALE * LOG2E; }
    else if (mat == 1) { src = Wkv; ldw = 512; cb = 0;   }
    else if (mat == 2) { src = Wkv; ldw = 512; cb = 256; }
    else               { src = Wp;  ldw = 256; cb = 0;   }
    {
        const int rl = t >> 4, c4 = (t & 15) * 4;
#pragma unroll
        for (int rr = 0; rr < 4; ++rr) {
            float4 v = *(const float4*)&src[(long long)(kr0 + rr * 16 + rl) * ldw + cb + nc0 + c4];
            T[rr * 16 + rl][c4 + 0] = v.x; T[rr * 16 + rl][c4 + 1] = v.y;
            T[rr * 16 + rl][c4 + 2] = v.z; T[rr * 16 + rl][c4 + 3] = v.w;
        }
    }
    __syncthreads();
    {
        const int nl = t >> 2, kl0 = (t & 3) * 16;
        const long long orow = (long long)(mat * 256 + nc0 + nl) * 256 + kr0 + kl0;
        union { unsigned short s[16]; uint4 u[2]; } ph;
#pragma unroll
        for (int j = 0; j < 16; ++j)
            ph.s[j] = f2h(T[kl0 + j][nl] * sc);
        *(uint4*)&wfp[orow] = ph.u[0];
        *(uint4*)&wfp[orow + 8] = ph.u[1];
    }
}

// ------------------------- K1: QKV fp16 MFMA GEMM, barrier-free K-loop
// grid (128, 12), block 256. W staged once; X fragments direct from global.
__global__ __launch_bounds__(256) void gemm_qkv(
    const float* __restrict__ query, const float* __restrict__ sim,
    const unsigned short* __restrict__ wfp,
    const float* __restrict__ bq, const float* __restrict__ bkv,
    unsigned short* __restrict__ qbuf, unsigned short* __restrict__ kbuf,
    unsigned short* __restrict__ vTb)
{
    __shared__ unsigned short Ws[64 * 264];      // [n 0..63][k 0..255] pad->264

    const int t = threadIdx.x, wave = t >> 6, lane = t & 63;
    const int col = lane & 15, quad = lane >> 4;
    const int by = blockIdx.y;
    const int kind = by >> 2;             // 0=Q 1=K 2=V
    const int n0 = (by & 3) * 64;
    const int m0 = blockIdx.x * 64;
    const float* __restrict__ X = (kind == 0) ? query : sim;
    const int wrow0 = kind * 256 + n0;

    // stage W once: thread t -> row t>>2, 64-half segment (t&3)*64
    {
        const int r = t >> 2, seg = (t & 3) * 64;
#pragma unroll
        for (int j = 0; j < 8; ++j) {
            uint4 w = *(const uint4*)&wfp[(long long)(wrow0 + r) * 256 + seg + j * 8];
            *(uint4*)&Ws[r * 264 + seg + j * 8] = w;
        }
    }
    __syncthreads();

    const f32x4 zero = {0.f, 0.f, 0.f, 0.f};
    f32x4 acc[4] = {zero, zero, zero, zero};

#pragma unroll
    for (int kt = 0; kt < 8; ++kt) {
        const int k0 = kt * 32;
        if (kind < 2) {
            const float* xp = &X[(long long)(m0 + wave * 16 + col) * 256 + k0 + quad * 8];
            float4 xa = *(const float4*)xp;
            float4 xb = *(const float4*)(xp + 4);
            half8 a = {(_Float16)xa.x, (_Float16)xa.y, (_Float16)xa.z, (_Float16)xa.w,
                       (_Float16)xb.x, (_Float16)xb.y, (_Float16)xb.z, (_Float16)xb.w};
#pragma unroll
            for (int nt = 0; nt < 4; ++nt) {
                half8 b = *(const half8*)(Ws + (nt * 16 + col) * 264 + k0 + quad * 8);
                acc[nt] = __builtin_amdgcn_mfma_f32_16x16x32_f16(a, b, acc[nt], 0, 0, 0);
            }
        } else {
            half8 a = *(const half8*)(Ws + (wave * 16 + col) * 264 + k0 + quad * 8);
#pragma unroll
            for (int nt = 0; nt < 4; ++nt) {
                const float* xp = &X[(long long)(m0 + nt * 16 + col) * 256 + k0 + quad * 8];
                float4 xa = *(const float4*)xp;
                float4 xb = *(const float4*)(xp + 4);
                half8 b = {(_Float16)xa.x, (_Float16)xa.y, (_Float16)xa.z, (_Float16)xa.w,
                           (_Float16)xb.x, (_Float16)xb.y, (_Float16)xb.z, (_Float16)xb.w};
                acc[nt] = __builtin_amdgcn_mfma_f32_16x16x32_f16(a, b, acc[nt], 0, 0, 0);
            }
        }
    }

    if (kind == 0) {
#pragma unroll
        for (int nt = 0; nt < 4; ++nt) {
            int n = n0 + nt * 16 + col;
            int h = n >> 5, d = n & 31;
            float bias = bq[n] * (SCALE * LOG2E);
#pragma unroll
            for (int r = 0; r < 4; ++r) {
                int mg = m0 + wave * 16 + quad * 4 + r;
                int b = mg >> 12, sidx = mg & 4095;
                qbuf[((long long)(b * 8 + h) * 4096 + sidx) * 32 + d] = f2bf(acc[nt][r] + bias);
            }
        }
    } else if (kind == 1) {
#pragma unroll
        for (int nt = 0; nt < 4; ++nt) {
            int n = n0 + nt * 16 + col;
            int h = n >> 5, d = n & 31;
            float bias = bkv[n];
#pragma unroll
            for (int r = 0; r < 4; ++r) {
                int mg = m0 + wave * 16 + quad * 4 + r;
                int b = mg >> 12, sidx = mg & 4095;
                kbuf[((long long)(b * 8 + h) * 4096 + sidx) * 32 + d] = f2bf(acc[nt][r] + bias);
            }
        }
    } else {
#pragma unroll
        for (int nt = 0; nt < 4; ++nt) {
            int s = m0 + nt * 16 + col;
            int b = s >> 12, sidx = s & 4095;
#pragma unroll
            for (int r = 0; r < 4; ++r) {
                int dcol = n0 + wave * 16 + quad * 4 + r;
                int h = dcol >> 5, dd = dcol & 31;
                float bias = bkv[256 + dcol];
                vTb[((long long)((b * 8 + h) * 32 + dd)) * 4096 + sidx] = f2bf(acc[nt][r] + bias);
            }
        }
    }
}

// ------------------------------------------------------------ K2: flash MFMA
// grid 2048 = ks(4) x bh(16) x qb(32); block 256 (4 waves x 32 q), 8 kt each.
// fp16 unnormalized partials + fp32 l per split.
__global__ __launch_bounds__(256) void flash_mfma(
    const unsigned short* __restrict__ qbuf,
    const unsigned short* __restrict__ kbuf,
    const unsigned short* __restrict__ vT,
    unsigned short* __restrict__ xpart, float* __restrict__ lpart)
{
    __shared__ unsigned short Ks[128 * 40];
    __shared__ unsigned short Vt[32 * 152];
    __shared__ unsigned short Pb[8][640];

    const int t = threadIdx.x;
    const int wave = t >> 6, lane = t & 63;
    const int col = lane & 15, quad = lane >> 4;
    const int qb = blockIdx.x & 31;
    const int bh = (blockIdx.x >> 5) & 15;
    const int ks = blockIdx.x >> 9;          // 0..3
    const int q0 = qb * 128 + wave * 32;
    const long long kvbase = (long long)bh * 4096 * 32;
    unsigned short* pb0 = Pb[wave * 2];
    unsigned short* pb1 = Pb[wave * 2 + 1];

    const short8 qf0 = *(const short8*)(qbuf + kvbase + (long long)(q0 + col) * 32 + quad * 8);
    const short8 qf1 = *(const short8*)(qbuf + kvbase + (long long)(q0 + 16 + col) * 32 + quad * 8);

    const f32x4 zero = {0.f, 0.f, 0.f, 0.f};
    f32x4 o00 = zero, o01 = zero, o10 = zero, o11 = zero;
    float l0 = 0.f, l1 = 0.f;

    const int krow = t >> 2, kpart = (t & 3) * 8;
    const int vrow = t >> 4, vpart = (t & 15) * 8;

    for (int kt0 = 0; kt0 < 8; ++kt0) {
        const int kt = ks * 8 + kt0;
        uint4 kg0 = *(const uint4*)(kbuf + kvbase + (long long)(kt * 128 + krow) * 32 + kpart);
        uint4 kg1 = *(const uint4*)(kbuf + kvbase + (long long)(kt * 128 + krow + 64) * 32 + kpart);
        uint4 vg0 = *(const uint4*)(vT + ((long long)(bh * 32 + vrow)) * 4096 + kt * 128 + vpart);
        uint4 vg1 = *(const uint4*)(vT + ((long long)(bh * 32 + vrow + 16)) * 4096 + kt * 128 + vpart);
        __syncthreads();
        *(uint4*)(Ks + krow * 40 + kpart) = kg0;
        *(uint4*)(Ks + (krow + 64) * 40 + kpart) = kg1;
        *(uint4*)(Vt + vrow * 152 + vpart) = vg0;
        *(uint4*)(Vt + (vrow + 16) * 152 + vpart) = vg1;
        __syncthreads();

#pragma unroll
        for (int sb = 0; sb < 4; ++sb) {
            const int kb = sb * 32;
            short8 a0 = *(const short8*)(Ks + (kb + col) * 40 + quad * 8);
            short8 a1 = *(const short8*)(Ks + (kb + 16 + col) * 40 + quad * 8);
            short8 v0 = *(const short8*)(Vt + col * 152 + kb + quad * 8);
            short8 v1 = *(const short8*)(Vt + (16 + col) * 152 + kb + quad * 8);
            // ---- q-tile 0
            {
                f32x4 c0 = __builtin_amdgcn_mfma_f32_16x16x32_bf16(a0, qf0, zero, 0, 0, 0);
                f32x4 c1 = __builtin_amdgcn_mfma_f32_16x16x32_bf16(a1, qf0, zero, 0, 0, 0);
                float p0 = fexp2(c0[0]), p1 = fexp2(c0[1]), p2 = fexp2(c0[2]), p3 = fexp2(c0[3]);
                float p4 = fexp2(c1[0]), p5 = fexp2(c1[1]), p6 = fexp2(c1[2]), p7 = fexp2(c1[3]);
                l0 += ((p0 + p1) + (p2 + p3)) + ((p4 + p5) + (p6 + p7));
                uint2 w0 = make_uint2(pk_bf16(p0, p1), pk_bf16(p2, p3));
                uint2 w1 = make_uint2(pk_bf16(p4, p5), pk_bf16(p6, p7));
                *(uint2*)(pb0 + col * 40 + quad * 4) = w0;
                *(uint2*)(pb0 + col * 40 + 16 + quad * 4) = w1;
                short8 pf = *(const short8*)(pb0 + col * 40 + quad * 8);
                o00 = __builtin_amdgcn_mfma_f32_16x16x32_bf16(v0, pf, o00, 0, 0, 0);
                o01 = __builtin_amdgcn_mfma_f32_16x16x32_bf16(v1, pf, o01, 0, 0, 0);
            }
            // ---- q-tile 1 (reuse a0,a1,v0,v1)
            {
                f32x4 c0 = __builtin_amdgcn_mfma_f32_16x16x32_bf16(a0, qf1, zero, 0, 0, 0);
                f32x4 c1 = __builtin_amdgcn_mfma_f32_16x16x32_bf16(a1, qf1, zero, 0, 0, 0);
                float p0 = fexp2(c0[0]), p1 = fexp2(c0[1]), p2 = fexp2(c0[2]), p3 = fexp2(c0[3]);
                float p4 = fexp2(c1[0]), p5 = fexp2(c1[1]), p6 = fexp2(c1[2]), p7 = fexp2(c1[3]);
                l1 += ((p0 + p1) + (p2 + p3)) + ((p4 + p5) + (p6 + p7));
                uint2 w0 = make_uint2(pk_bf16(p0, p1), pk_bf16(p2, p3));
                uint2 w1 = make_uint2(pk_bf16(p4, p5), pk_bf16(p6, p7));
                *(uint2*)(pb1 + col * 40 + quad * 4) = w0;
                *(uint2*)(pb1 + col * 40 + 16 + quad * 4) = w1;
                short8 pf = *(const short8*)(pb1 + col * 40 + quad * 8);
                o10 = __builtin_amdgcn_mfma_f32_16x16x32_bf16(v0, pf, o10, 0, 0, 0);
                o11 = __builtin_amdgcn_mfma_f32_16x16x32_bf16(v1, pf, o11, 0, 0, 0);
            }
        }
    }

    l0 += __shfl_xor(l0, 16, 64); l0 += __shfl_xor(l0, 32, 64);
    l1 += __shfl_xor(l1, 16, 64); l1 += __shfl_xor(l1, 32, 64);

    const int b = bh >> 3, hh = bh & 7;
    unsigned short* xp = xpart + (long long)ks * 2097152;
    {
        unsigned short* rp = xp + ((long long)(b * 4096 + q0 + col)) * 256 + hh * 32;
        union { unsigned short s[4]; uint2 u; } pa, pb2;
#pragma unroll
        for (int r = 0; r < 4; ++r) { pa.s[r] = f2h(o00[r]); pb2.s[r] = f2h(o01[r]); }
        *(uint2*)(rp + quad * 4) = pa.u;
        *(uint2*)(rp + 16 + quad * 4) = pb2.u;
    }
    {
        unsigned short* rp = xp + ((long long)(b * 4096 + q0 + 16 + col)) * 256 + hh * 32;
        union { unsigned short s[4]; uint2 u; } pa, pb2;
#pragma unroll
        for (int r = 0; r < 4; ++r) { pa.s[r] = f2h(o10[r]); pb2.s[r] = f2h(o11[r]); }
        *(uint2*)(rp + quad * 4) = pa.u;
        *(uint2*)(rp + 16 + quad * 4) = pb2.u;
    }

    if (quad == 0)      lpart[ks * 65536 + bh * 4096 + q0 + col] = l0;
    else if (quad == 1) lpart[ks * 65536 + bh * 4096 + q0 + 16 + col] = l1;
}

// ------------- K3: combine(4 fp16 partials) + 1/l + out-proj, barrier-free
// grid (128, 4), block 256. Wp^T staged once; A built per-lane from global.
__global__ __launch_bounds__(256) void gemm_outp(
    const unsigned short* __restrict__ xpart, const float* __restrict__ lpart,
    const unsigned short* __restrict__ wfp,
    const float* __restrict__ bp, float* __restrict__ out)
{
    __shared__ unsigned short Ws[64 * 264];

    const int t = threadIdx.x, wave = t >> 6, lane = t & 63;
    const int col = lane & 15, quad = lane >> 4;
    const int n0 = blockIdx.y * 64;
    const int m0 = blockIdx.x * 64;
    const int wrow0 = 768 + n0;

    {
        const int r = t >> 2, seg = (t & 3) * 64;
#pragma unroll
        for (int j = 0; j < 8; ++j) {
            uint4 w = *(const uint4*)&wfp[(long long)(wrow0 + r) * 256 + seg + j * 8];
            *(uint4*)&Ws[r * 264 + seg + j * 8] = w;
        }
    }
    __syncthreads();

    const int row = m0 + wave * 16 + col;
    const int bidx = row >> 12, sr = row & 4095;

    const f32x4 zero = {0.f, 0.f, 0.f, 0.f};
    f32x4 acc[4] = {zero, zero, zero, zero};

#pragma unroll
    for (int kt = 0; kt < 8; ++kt) {
        const int k0 = kt * 32;
        float lsum = 0.f;
#pragma unroll
        for (int ss = 0; ss < 4; ++ss)
            lsum += lpart[ss * 65536 + (bidx * 8 + kt) * 4096 + sr];
        const float linv = 1.f / lsum;

        union { unsigned short s[8]; uint4 u; } p[4];
#pragma unroll
        for (int ss = 0; ss < 4; ++ss)
            p[ss].u = *(const uint4*)&xpart[(long long)ss * 2097152 +
                                            (long long)row * 256 + k0 + quad * 8];
        _Float16 ah[8], al[8];
#pragma unroll
        for (int j = 0; j < 8; ++j) {
            float xv = (h2f(p[0].s[j]) + h2f(p[1].s[j]) +
                        h2f(p[2].s[j]) + h2f(p[3].s[j])) * linv;
            _Float16 h = (_Float16)xv;
            ah[j] = h;
            al[j] = (_Float16)(xv - (float)h);
        }
        half8 a_h = {ah[0], ah[1], ah[2], ah[3], ah[4], ah[5], ah[6], ah[7]};
        half8 a_l = {al[0], al[1], al[2], al[3], al[4], al[5], al[6], al[7]};
#pragma unroll
        for (int nt = 0; nt < 4; ++nt) {
            half8 b = *(const half8*)(Ws + (nt * 16 + col) * 264 + k0 + quad * 8);
            acc[nt] = __builtin_amdgcn_mfma_f32_16x16x32_f16(a_h, b, acc[nt], 0, 0, 0);
            acc[nt] = __builtin_amdgcn_mfma_f32_16x16x32_f16(a_l, b, acc[nt], 0, 0, 0);
        }
    }

#pragma unroll
    for (int nt = 0; nt < 4; ++nt) {
        int n = n0 + nt * 16 + col;
        float bias = bp[n];
#pragma unroll
        for (int rr = 0; rr < 4; ++rr) {
            int mg = m0 + wave * 16 + quad * 4 + rr;
            out[(long long)mg * 256 + n] = acc[nt][rr] + bias;
        }
    }
}

extern "C" void kernel_launch(void* const* d_in, const int* in_sizes, int n_in,
                              void* d_out, int out_size, void* d_ws, size_t ws_size,
                              hipStream_t stream) {
    const float* query = (const float*)d_in[0];
    const float* sim   = (const float*)d_in[1];
    const float* Wq    = (const float*)d_in[2];
    const float* bq    = (const float*)d_in[3];
    const float* Wkv   = (const float*)d_in[4];
    const float* bkv   = (const float*)d_in[5];
    const float* Wp    = (const float*)d_in[6];
    const float* bp    = (const float*)d_in[7];
    float* out = (float*)d_out;

    unsigned short* wsb = (unsigned short*)d_ws;
    unsigned short* qbuf = wsb;                        // 2,097,152 shorts
    unsigned short* kbuf = wsb + 2097152;
    unsigned short* vT   = wsb + 4194304;              // ends 6,291,456
    unsigned short* wfp  = wsb + 6291456;              // 262,144 fp16
    unsigned short* xpart = wsb + 6553600;             // 4 x 2,097,152 fp16
    float* lpart = (float*)(wsb + 14942208);           // 4 x 65,536 fp32

    prep      <<<dim3(64),      256, 0, stream>>>(Wq, Wkv, Wp, wfp);
    gemm_qkv  <<<dim3(128, 12), 256, 0, stream>>>(query, sim, wfp, bq, bkv,
                                                  qbuf, kbuf, vT);
    flash_mfma<<<dim3(2048),    256, 0, stream>>>(qbuf, kbuf, vT, xpart, lpart);
    gemm_outp <<<dim3(128, 4),  256, 0, stream>>>(xpart, lpart, wfp, bp, out);
}

// Round 13
// 156.045 us; speedup vs baseline: 1.1691x; 1.1691x over previous
//
#include <hip/hip_runtime.h>
#include <hip/hip_bf16.h>
#include <math.h>

// CrossAttention: B=2, S=4096, DIM=256, NH=8, DH=32.
// R12 = best-of halves: R10's staged-LDS GEMMs (rest=92us proven) +
// R11's flash (ks=4, fp16 partials, 64.4us proven); outp combines 4 fp16
// partials inside R10's staged structure.
// LESSONS: staged-LDS+barriers beats barrier-free direct-global for these
// small GEMMs (R11: coalescing loss > barrier cost). SQ_LDS_BANK_CONFLICT
// is op-width-inherent, not a lever [R10]. Strides mult of 8 shorts
// [R3/R4/R6]; >=4 blocks/CU [R9]; flash K/V via LDS [R5].

#define SCALE 0.17677669529663687f   // 32^-0.5
#define LOG2E 1.4426950408889634f

typedef __attribute__((ext_vector_type(8))) short short8;
typedef __attribute__((ext_vector_type(8))) _Float16 half8;
typedef __attribute__((ext_vector_type(4))) float f32x4;

static __device__ __forceinline__ unsigned short f2bf(float x) {
    union { float f; unsigned int u; } v; v.f = x;
    unsigned int r = v.u + 0x7fff + ((v.u >> 16) & 1);   // RNE
    return (unsigned short)(r >> 16);
}
static __device__ __forceinline__ float fexp2(float x) {
#if __has_builtin(__builtin_amdgcn_exp2f)
    return __builtin_amdgcn_exp2f(x);
#else
    float r; asm("v_exp_f32 %0, %1" : "=v"(r) : "v"(x)); return r;
#endif
}
static __device__ __forceinline__ unsigned int pk_bf16(float a, float b) {
    unsigned int r;
    asm("v_cvt_pk_bf16_f32 %0, %1, %2" : "=v"(r) : "v"(a), "v"(b));
    return r;
}
static __device__ __forceinline__ unsigned short f2h(float x) {
    _Float16 h = (_Float16)x;
    union { _Float16 h; unsigned short s; } u; u.h = h;
    return u.s;
}
static __device__ __forceinline__ float h2f(unsigned short s) {
    union { _Float16 h; unsigned short s; } u; u.s = s;
    return (float)u.h;
}

// -------------------------------------------------- K0: W^T -> fp16 prep
__global__ __launch_bounds__(256) void prep(
    const float* __restrict__ Wq, const float* __restrict__ Wkv,
    const float* __restrict__ Wp, unsigned short* __restrict__ wfp)
{
    __shared__ float T[64][68];
    const int bb = blockIdx.x, t = threadIdx.x;
    const int mat = bb >> 4, tile = bb & 15;
    const int kr0 = (tile >> 2) * 64;
    const int nc0 = (tile & 3) * 64;
    const float* src; int ldw, cb; float sc = 1.f;
    if (mat == 0)      { src = Wq;  ldw = 256; cb = 0;   sc = SCALE * LOG2E; }
    else if (mat == 1) { src = Wkv; ldw = 512; cb = 0;   }
    else if (mat == 2) { src = Wkv; ldw = 512; cb = 256; }
    else               { src = Wp;  ldw = 256; cb = 0;   }
    {
        const int rl = t >> 4, c4 = (t & 15) * 4;
#pragma unroll
        for (int rr = 0; rr < 4; ++rr) {
            float4 v = *(const float4*)&src[(long long)(kr0 + rr * 16 + rl) * ldw + cb + nc0 + c4];
            T[rr * 16 + rl][c4 + 0] = v.x; T[rr * 16 + rl][c4 + 1] = v.y;
            T[rr * 16 + rl][c4 + 2] = v.z; T[rr * 16 + rl][c4 + 3] = v.w;
        }
    }
    __syncthreads();
    {
        const int nl = t >> 2, kl0 = (t & 3) * 16;
        const long long orow = (long long)(mat * 256 + nc0 + nl) * 256 + kr0 + kl0;
        union { unsigned short s[16]; uint4 u[2]; } ph;
#pragma unroll
        for (int j = 0; j < 16; ++j)
            ph.s[j] = f2h(T[kl0 + j][nl] * sc);
        *(uint4*)&wfp[orow] = ph.u[0];
        *(uint4*)&wfp[orow + 8] = ph.u[1];
    }
}

// --------------------------------------------- K1: QKV fp16 MFMA GEMM (R10)
// grid (128, 12), block 256. X converted fp32->fp16 during staging.
__global__ __launch_bounds__(256) void gemm_qkv(
    const float* __restrict__ query, const float* __restrict__ sim,
    const unsigned short* __restrict__ wfp,
    const float* __restrict__ bq, const float* __restrict__ bkv,
    unsigned short* __restrict__ qbuf, unsigned short* __restrict__ kbuf,
    unsigned short* __restrict__ vTb)
{
    __shared__ unsigned short Xs[64 * 40], Ws[64 * 40];

    const int t = threadIdx.x, wave = t >> 6, lane = t & 63;
    const int col = lane & 15, quad = lane >> 4;
    const int by = blockIdx.y;
    const int kind = by >> 2;             // 0=Q 1=K 2=V
    const int n0 = (by & 3) * 64;
    const int m0 = blockIdx.x * 64;
    const float* __restrict__ X = (kind == 0) ? query : sim;
    const int wrow0 = kind * 256 + n0;
    const int srow = t >> 2, spart = (t & 3) * 8;

    const f32x4 zero = {0.f, 0.f, 0.f, 0.f};
    f32x4 acc[4] = {zero, zero, zero, zero};

    for (int kt = 0; kt < 8; ++kt) {
        const int k0 = kt * 32;
        const float* xp = &X[(long long)(m0 + srow) * 256 + k0 + spart];
        float4 xa = *(const float4*)xp;
        float4 xb = *(const float4*)(xp + 4);
        float xv[8] = {xa.x, xa.y, xa.z, xa.w, xb.x, xb.y, xb.z, xb.w};
        union { unsigned short s[8]; uint4 u; } ph;
#pragma unroll
        for (int j = 0; j < 8; ++j) ph.s[j] = f2h(xv[j]);
        uint4 wh = *(const uint4*)&wfp[(long long)(wrow0 + srow) * 256 + k0 + spart];
        __syncthreads();
        *(uint4*)&Xs[srow * 40 + spart] = ph.u;
        *(uint4*)&Ws[srow * 40 + spart] = wh;
        __syncthreads();

        if (kind < 2) {
            half8 a = *(const half8*)(Xs + (wave * 16 + col) * 40 + quad * 8);
#pragma unroll
            for (int nt = 0; nt < 4; ++nt) {
                half8 b = *(const half8*)(Ws + (nt * 16 + col) * 40 + quad * 8);
                acc[nt] = __builtin_amdgcn_mfma_f32_16x16x32_f16(a, b, acc[nt], 0, 0, 0);
            }
        } else {
            half8 a = *(const half8*)(Ws + (wave * 16 + col) * 40 + quad * 8);
#pragma unroll
            for (int nt = 0; nt < 4; ++nt) {
                half8 b = *(const half8*)(Xs + (nt * 16 + col) * 40 + quad * 8);
                acc[nt] = __builtin_amdgcn_mfma_f32_16x16x32_f16(a, b, acc[nt], 0, 0, 0);
            }
        }
    }

    if (kind == 0) {
#pragma unroll
        for (int nt = 0; nt < 4; ++nt) {
            int n = n0 + nt * 16 + col;
            int h = n >> 5, d = n & 31;
            float bias = bq[n] * (SCALE * LOG2E);
#pragma unroll
            for (int r = 0; r < 4; ++r) {
                int mg = m0 + wave * 16 + quad * 4 + r;
                int b = mg >> 12, sidx = mg & 4095;
                qbuf[((long long)(b * 8 + h) * 4096 + sidx) * 32 + d] = f2bf(acc[nt][r] + bias);
            }
        }
    } else if (kind == 1) {
#pragma unroll
        for (int nt = 0; nt < 4; ++nt) {
            int n = n0 + nt * 16 + col;
            int h = n >> 5, d = n & 31;
            float bias = bkv[n];
#pragma unroll
            for (int r = 0; r < 4; ++r) {
                int mg = m0 + wave * 16 + quad * 4 + r;
                int b = mg >> 12, sidx = mg & 4095;
                kbuf[((long long)(b * 8 + h) * 4096 + sidx) * 32 + d] = f2bf(acc[nt][r] + bias);
            }
        }
    } else {
#pragma unroll
        for (int nt = 0; nt < 4; ++nt) {
            int s = m0 + nt * 16 + col;
            int b = s >> 12, sidx = s & 4095;
#pragma unroll
            for (int r = 0; r < 4; ++r) {
                int dcol = n0 + wave * 16 + quad * 4 + r;
                int h = dcol >> 5, dd = dcol & 31;
                float bias = bkv[256 + dcol];
                vTb[((long long)((b * 8 + h) * 32 + dd)) * 4096 + sidx] = f2bf(acc[nt][r] + bias);
            }
        }
    }
}

// ------------------------------------------------------------ K2: flash MFMA
// VERBATIM R11 (64.4us). grid 2048 = ks(4) x bh(16) x qb(32); block 256.
__global__ __launch_bounds__(256) void flash_mfma(
    const unsigned short* __restrict__ qbuf,
    const unsigned short* __restrict__ kbuf,
    const unsigned short* __restrict__ vT,
    unsigned short* __restrict__ xpart, float* __restrict__ lpart)
{
    __shared__ unsigned short Ks[128 * 40];
    __shared__ unsigned short Vt[32 * 152];
    __shared__ unsigned short Pb[8][640];

    const int t = threadIdx.x;
    const int wave = t >> 6, lane = t & 63;
    const int col = lane & 15, quad = lane >> 4;
    const int qb = blockIdx.x & 31;
    const int bh = (blockIdx.x >> 5) & 15;
    const int ks = blockIdx.x >> 9;          // 0..3
    const int q0 = qb * 128 + wave * 32;
    const long long kvbase = (long long)bh * 4096 * 32;
    unsigned short* pb0 = Pb[wave * 2];
    unsigned short* pb1 = Pb[wave * 2 + 1];

    const short8 qf0 = *(const short8*)(qbuf + kvbase + (long long)(q0 + col) * 32 + quad * 8);
    const short8 qf1 = *(const short8*)(qbuf + kvbase + (long long)(q0 + 16 + col) * 32 + quad * 8);

    const f32x4 zero = {0.f, 0.f, 0.f, 0.f};
    f32x4 o00 = zero, o01 = zero, o10 = zero, o11 = zero;
    float l0 = 0.f, l1 = 0.f;

    const int krow = t >> 2, kpart = (t & 3) * 8;
    const int vrow = t >> 4, vpart = (t & 15) * 8;

    for (int kt0 = 0; kt0 < 8; ++kt0) {
        const int kt = ks * 8 + kt0;
        uint4 kg0 = *(const uint4*)(kbuf + kvbase + (long long)(kt * 128 + krow) * 32 + kpart);
        uint4 kg1 = *(const uint4*)(kbuf + kvbase + (long long)(kt * 128 + krow + 64) * 32 + kpart);
        uint4 vg0 = *(const uint4*)(vT + ((long long)(bh * 32 + vrow)) * 4096 + kt * 128 + vpart);
        uint4 vg1 = *(const uint4*)(vT + ((long long)(bh * 32 + vrow + 16)) * 4096 + kt * 128 + vpart);
        __syncthreads();
        *(uint4*)(Ks + krow * 40 + kpart) = kg0;
        *(uint4*)(Ks + (krow + 64) * 40 + kpart) = kg1;
        *(uint4*)(Vt + vrow * 152 + vpart) = vg0;
        *(uint4*)(Vt + (vrow + 16) * 152 + vpart) = vg1;
        __syncthreads();

#pragma unroll
        for (int sb = 0; sb < 4; ++sb) {
            const int kb = sb * 32;
            short8 a0 = *(const short8*)(Ks + (kb + col) * 40 + quad * 8);
            short8 a1 = *(const short8*)(Ks + (kb + 16 + col) * 40 + quad * 8);
            short8 v0 = *(const short8*)(Vt + col * 152 + kb + quad * 8);
            short8 v1 = *(const short8*)(Vt + (16 + col) * 152 + kb + quad * 8);
            // ---- q-tile 0
            {
                f32x4 c0 = __builtin_amdgcn_mfma_f32_16x16x32_bf16(a0, qf0, zero, 0, 0, 0);
                f32x4 c1 = __builtin_amdgcn_mfma_f32_16x16x32_bf16(a1, qf0, zero, 0, 0, 0);
                float p0 = fexp2(c0[0]), p1 = fexp2(c0[1]), p2 = fexp2(c0[2]), p3 = fexp2(c0[3]);
                float p4 = fexp2(c1[0]), p5 = fexp2(c1[1]), p6 = fexp2(c1[2]), p7 = fexp2(c1[3]);
                l0 += ((p0 + p1) + (p2 + p3)) + ((p4 + p5) + (p6 + p7));
                uint2 w0 = make_uint2(pk_bf16(p0, p1), pk_bf16(p2, p3));
                uint2 w1 = make_uint2(pk_bf16(p4, p5), pk_bf16(p6, p7));
                *(uint2*)(pb0 + col * 40 + quad * 4) = w0;
                *(uint2*)(pb0 + col * 40 + 16 + quad * 4) = w1;
                short8 pf = *(const short8*)(pb0 + col * 40 + quad * 8);
                o00 = __builtin_amdgcn_mfma_f32_16x16x32_bf16(v0, pf, o00, 0, 0, 0);
                o01 = __builtin_amdgcn_mfma_f32_16x16x32_bf16(v1, pf, o01, 0, 0, 0);
            }
            // ---- q-tile 1 (reuse a0,a1,v0,v1)
            {
                f32x4 c0 = __builtin_amdgcn_mfma_f32_16x16x32_bf16(a0, qf1, zero, 0, 0, 0);
                f32x4 c1 = __builtin_amdgcn_mfma_f32_16x16x32_bf16(a1, qf1, zero, 0, 0, 0);
                float p0 = fexp2(c0[0]), p1 = fexp2(c0[1]), p2 = fexp2(c0[2]), p3 = fexp2(c0[3]);
                float p4 = fexp2(c1[0]), p5 = fexp2(c1[1]), p6 = fexp2(c1[2]), p7 = fexp2(c1[3]);
                l1 += ((p0 + p1) + (p2 + p3)) + ((p4 + p5) + (p6 + p7));
                uint2 w0 = make_uint2(pk_bf16(p0, p1), pk_bf16(p2, p3));
                uint2 w1 = make_uint2(pk_bf16(p4, p5), pk_bf16(p6, p7));
                *(uint2*)(pb1 + col * 40 + quad * 4) = w0;
                *(uint2*)(pb1 + col * 40 + 16 + quad * 4) = w1;
                short8 pf = *(const short8*)(pb1 + col * 40 + quad * 8);
                o10 = __builtin_amdgcn_mfma_f32_16x16x32_bf16(v0, pf, o10, 0, 0, 0);
                o11 = __builtin_amdgcn_mfma_f32_16x16x32_bf16(v1, pf, o11, 0, 0, 0);
            }
        }
    }

    l0 += __shfl_xor(l0, 16, 64); l0 += __shfl_xor(l0, 32, 64);
    l1 += __shfl_xor(l1, 16, 64); l1 += __shfl_xor(l1, 32, 64);

    const int b = bh >> 3, hh = bh & 7;
    unsigned short* xp = xpart + (long long)ks * 2097152;
    {
        unsigned short* rp = xp + ((long long)(b * 4096 + q0 + col)) * 256 + hh * 32;
        union { unsigned short s[4]; uint2 u; } pa, pb2;
#pragma unroll
        for (int r = 0; r < 4; ++r) { pa.s[r] = f2h(o00[r]); pb2.s[r] = f2h(o01[r]); }
        *(uint2*)(rp + quad * 4) = pa.u;
        *(uint2*)(rp + 16 + quad * 4) = pb2.u;
    }
    {
        unsigned short* rp = xp + ((long long)(b * 4096 + q0 + 16 + col)) * 256 + hh * 32;
        union { unsigned short s[4]; uint2 u; } pa, pb2;
#pragma unroll
        for (int r = 0; r < 4; ++r) { pa.s[r] = f2h(o10[r]); pb2.s[r] = f2h(o11[r]); }
        *(uint2*)(rp + quad * 4) = pa.u;
        *(uint2*)(rp + 16 + quad * 4) = pb2.u;
    }

    if (quad == 0)      lpart[ks * 65536 + bh * 4096 + q0 + col] = l0;
    else if (quad == 1) lpart[ks * 65536 + bh * 4096 + q0 + 16 + col] = l1;
}

// ------- K3: combine 4 fp16 partials + 1/l + out-proj (R10 staged structure)
// grid (128, 4), block 256.
__global__ __launch_bounds__(256) void gemm_outp(
    const unsigned short* __restrict__ xpart, const float* __restrict__ lpart,
    const unsigned short* __restrict__ wfp,
    const float* __restrict__ bp, float* __restrict__ out)
{
    __shared__ unsigned short XsH[64 * 40], XsL[64 * 40], Ws[64 * 40];

    const int t = threadIdx.x, wave = t >> 6, lane = t & 63;
    const int col = lane & 15, quad = lane >> 4;
    const int n0 = blockIdx.y * 64;
    const int m0 = blockIdx.x * 64;
    const int wrow0 = 768 + n0;
    const int srow = t >> 2, spart = (t & 3) * 8;
    const int r = m0 + srow;
    const int bidx = r >> 12, s = r & 4095;

    const f32x4 zero = {0.f, 0.f, 0.f, 0.f};
    f32x4 acc[4] = {zero, zero, zero, zero};

    for (int kt = 0; kt < 8; ++kt) {
        const int k0 = kt * 32;
        float lsum = lpart[(bidx * 8 + kt) * 4096 + s]
                   + lpart[65536 + (bidx * 8 + kt) * 4096 + s]
                   + lpart[131072 + (bidx * 8 + kt) * 4096 + s]
                   + lpart[196608 + (bidx * 8 + kt) * 4096 + s];
        const float linv = 1.f / lsum;

        union { unsigned short s4[8]; uint4 u; } p[4];
#pragma unroll
        for (int ss = 0; ss < 4; ++ss)
            p[ss].u = *(const uint4*)&xpart[(long long)ss * 2097152 +
                                            (long long)r * 256 + k0 + spart];
        union { unsigned short s4[8]; uint4 u; } ph, pl;
#pragma unroll
        for (int j = 0; j < 8; ++j) {
            float xv = (h2f(p[0].s4[j]) + h2f(p[1].s4[j]) +
                        h2f(p[2].s4[j]) + h2f(p[3].s4[j])) * linv;
            unsigned short h = f2h(xv);
            ph.s4[j] = h;
            pl.s4[j] = f2h(xv - h2f(h));
        }
        uint4 wh = *(const uint4*)&wfp[(long long)(wrow0 + srow) * 256 + k0 + spart];
        __syncthreads();
        *(uint4*)&XsH[srow * 40 + spart] = ph.u;
        *(uint4*)&XsL[srow * 40 + spart] = pl.u;
        *(uint4*)&Ws[srow * 40 + spart] = wh;
        __syncthreads();

        half8 a_h = *(const half8*)(XsH + (wave * 16 + col) * 40 + quad * 8);
        half8 a_l = *(const half8*)(XsL + (wave * 16 + col) * 40 + quad * 8);
#pragma unroll
        for (int nt = 0; nt < 4; ++nt) {
            half8 b = *(const half8*)(Ws + (nt * 16 + col) * 40 + quad * 8);
            acc[nt] = __builtin_amdgcn_mfma_f32_16x16x32_f16(a_h, b, acc[nt], 0, 0, 0);
            acc[nt] = __builtin_amdgcn_mfma_f32_16x16x32_f16(a_l, b, acc[nt], 0, 0, 0);
        }
    }

#pragma unroll
    for (int nt = 0; nt < 4; ++nt) {
        int n = n0 + nt * 16 + col;
        float bias = bp[n];
#pragma unroll
        for (int rr = 0; rr < 4; ++rr) {
            int mg = m0 + wave * 16 + quad * 4 + rr;
            out[(long long)mg * 256 + n] = acc[nt][rr] + bias;
        }
    }
}

extern "C" void kernel_launch(void* const* d_in, const int* in_sizes, int n_in,
                              void* d_out, int out_size, void* d_ws, size_t ws_size,
                              hipStream_t stream) {
    const float* query = (const float*)d_in[0];
    const float* sim   = (const float*)d_in[1];
    const float* Wq    = (const float*)d_in[2];
    const float* bq    = (const float*)d_in[3];
    const float* Wkv   = (const float*)d_in[4];
    const float* bkv   = (const float*)d_in[5];
    const float* Wp    = (const float*)d_in[6];
    const float* bp    = (const float*)d_in[7];
    float* out = (float*)d_out;

    unsigned short* wsb = (unsigned short*)d_ws;
    unsigned short* qbuf = wsb;                        // 2,097,152 shorts
    unsigned short* kbuf = wsb + 2097152;
    unsigned short* vT   = wsb + 4194304;              // ends 6,291,456
    unsigned short* wfp  = wsb + 6291456;              // 262,144 fp16
    unsigned short* xpart = wsb + 6553600;             // 4 x 2,097,152 fp16
    float* lpart = (float*)(wsb + 14942208);           // 4 x 65,536 fp32

    prep      <<<dim3(64),      256, 0, stream>>>(Wq, Wkv, Wp, wfp);
    gemm_qkv  <<<dim3(128, 12), 256, 0, stream>>>(query, sim, wfp, bq, bkv,
                                                  qbuf, kbuf, vT);
    flash_mfma<<<dim3(2048),    256, 0, stream>>>(qbuf, kbuf, vT, xpart, lpart);
    gemm_outp <<<dim3(128, 4),  256, 0, stream>>>(xpart, lpart, wfp, bp, out);
}

// Round 14
// 155.327 us; speedup vs baseline: 1.1745x; 1.0046x over previous
//
#include <hip/hip_runtime.h>
#include <hip/hip_bf16.h>
#include <math.h>

// CrossAttention: B=2, S=4096, DIM=256, NH=8, DH=32.
// R13 = R12 with gemm_qkv K/V-fused: K-blocks and V-blocks staged the SAME
// sim tile (K uses it as A, V as B) — one block now does both. Grid
// (128,12)->(128,8); sim read 8x->4x; staging/barrier/f2h work -33%.
// Flash is exp-throughput-bound (268M exps ~= 55us of quarter-rate trans
// pipe = 84% of its 64.8us) — left verbatim.
// LESSONS: staged-LDS+barriers > barrier-free direct-global here [R11];
// SQ_LDS_BANK_CONFLICT is op-width-inherent [R10]; strides mult of 8
// shorts [R3/R4/R6]; >=4 blocks/CU [R9]; flash K/V via LDS [R5].

#define SCALE 0.17677669529663687f   // 32^-0.5
#define LOG2E 1.4426950408889634f

typedef __attribute__((ext_vector_type(8))) short short8;
typedef __attribute__((ext_vector_type(8))) _Float16 half8;
typedef __attribute__((ext_vector_type(4))) float f32x4;

static __device__ __forceinline__ unsigned short f2bf(float x) {
    union { float f; unsigned int u; } v; v.f = x;
    unsigned int r = v.u + 0x7fff + ((v.u >> 16) & 1);   // RNE
    return (unsigned short)(r >> 16);
}
static __device__ __forceinline__ float fexp2(float x) {
#if __has_builtin(__builtin_amdgcn_exp2f)
    return __builtin_amdgcn_exp2f(x);
#else
    float r; asm("v_exp_f32 %0, %1" : "=v"(r) : "v"(x)); return r;
#endif
}
static __device__ __forceinline__ unsigned int pk_bf16(float a, float b) {
    unsigned int r;
    asm("v_cvt_pk_bf16_f32 %0, %1, %2" : "=v"(r) : "v"(a), "v"(b));
    return r;
}
static __device__ __forceinline__ unsigned short f2h(float x) {
    _Float16 h = (_Float16)x;
    union { _Float16 h; unsigned short s; } u; u.h = h;
    return u.s;
}
static __device__ __forceinline__ float h2f(unsigned short s) {
    union { _Float16 h; unsigned short s; } u; u.s = s;
    return (float)u.h;
}

// -------------------------------------------------- K0: W^T -> fp16 prep
__global__ __launch_bounds__(256) void prep(
    const float* __restrict__ Wq, const float* __restrict__ Wkv,
    const float* __restrict__ Wp, unsigned short* __restrict__ wfp)
{
    __shared__ float T[64][68];
    const int bb = blockIdx.x, t = threadIdx.x;
    const int mat = bb >> 4, tile = bb & 15;
    const int kr0 = (tile >> 2) * 64;
    const int nc0 = (tile & 3) * 64;
    const float* src; int ldw, cb; float sc = 1.f;
    if (mat == 0)      { src = Wq;  ldw = 256; cb = 0;   sc = SCALE * LOG2E; }
    else if (mat == 1) { src = Wkv; ldw = 512; cb = 0;   }
    else if (mat == 2) { src = Wkv; ldw = 512; cb = 256; }
    else               { src = Wp;  ldw = 256; cb = 0;   }
    {
        const int rl = t >> 4, c4 = (t & 15) * 4;
#pragma unroll
        for (int rr = 0; rr < 4; ++rr) {
            float4 v = *(const float4*)&src[(long long)(kr0 + rr * 16 + rl) * ldw + cb + nc0 + c4];
            T[rr * 16 + rl][c4 + 0] = v.x; T[rr * 16 + rl][c4 + 1] = v.y;
            T[rr * 16 + rl][c4 + 2] = v.z; T[rr * 16 + rl][c4 + 3] = v.w;
        }
    }
    __syncthreads();
    {
        const int nl = t >> 2, kl0 = (t & 3) * 16;
        const long long orow = (long long)(mat * 256 + nc0 + nl) * 256 + kr0 + kl0;
        union { unsigned short s[16]; uint4 u[2]; } ph;
#pragma unroll
        for (int j = 0; j < 16; ++j)
            ph.s[j] = f2h(T[kl0 + j][nl] * sc);
        *(uint4*)&wfp[orow] = ph.u[0];
        *(uint4*)&wfp[orow + 8] = ph.u[1];
    }
}

// ----------------------- K1: QKV fp16 MFMA GEMM, K/V fused per sim-tile
// grid (128, 8), block 256. by<4: Q (n0=by*64). by>=4: K+V (n0=(by-4)*64).
__global__ __launch_bounds__(256) void gemm_qkv(
    const float* __restrict__ query, const float* __restrict__ sim,
    const unsigned short* __restrict__ wfp,
    const float* __restrict__ bq, const float* __restrict__ bkv,
    unsigned short* __restrict__ qbuf, unsigned short* __restrict__ kbuf,
    unsigned short* __restrict__ vTb)
{
    __shared__ unsigned short Xs[64 * 40], WsA[64 * 40], WsB[64 * 40];

    const int t = threadIdx.x, wave = t >> 6, lane = t & 63;
    const int col = lane & 15, quad = lane >> 4;
    const int by = blockIdx.y;
    const bool isQ = (by < 4);
    const int n0 = (isQ ? by : by - 4) * 64;
    const int m0 = blockIdx.x * 64;
    const float* __restrict__ X = isQ ? query : sim;
    const int wrowA = (isQ ? 0 : 256) + n0;      // Wq or Wk rows
    const int wrowB = 512 + n0;                  // Wv rows (KV path only)
    const int srow = t >> 2, spart = (t & 3) * 8;

    const f32x4 zero = {0.f, 0.f, 0.f, 0.f};
    f32x4 accA[4] = {zero, zero, zero, zero};    // Q or K  (C[m=s][n=feat])
    f32x4 accV[4] = {zero, zero, zero, zero};    // V       (C[m=feat][n=s])

    for (int kt = 0; kt < 8; ++kt) {
        const int k0 = kt * 32;
        const float* xp = &X[(long long)(m0 + srow) * 256 + k0 + spart];
        float4 xa = *(const float4*)xp;
        float4 xb = *(const float4*)(xp + 4);
        float xv[8] = {xa.x, xa.y, xa.z, xa.w, xb.x, xb.y, xb.z, xb.w};
        union { unsigned short s[8]; uint4 u; } ph;
#pragma unroll
        for (int j = 0; j < 8; ++j) ph.s[j] = f2h(xv[j]);
        uint4 wa = *(const uint4*)&wfp[(long long)(wrowA + srow) * 256 + k0 + spart];
        uint4 wb;
        if (!isQ) wb = *(const uint4*)&wfp[(long long)(wrowB + srow) * 256 + k0 + spart];
        __syncthreads();
        *(uint4*)&Xs[srow * 40 + spart] = ph.u;
        *(uint4*)&WsA[srow * 40 + spart] = wa;
        if (!isQ) *(uint4*)&WsB[srow * 40 + spart] = wb;
        __syncthreads();

        half8 aX = *(const half8*)(Xs + (wave * 16 + col) * 40 + quad * 8);
#pragma unroll
        for (int nt = 0; nt < 4; ++nt) {
            half8 b = *(const half8*)(WsA + (nt * 16 + col) * 40 + quad * 8);
            accA[nt] = __builtin_amdgcn_mfma_f32_16x16x32_f16(aX, b, accA[nt], 0, 0, 0);
        }
        if (!isQ) {
            half8 aW = *(const half8*)(WsB + (wave * 16 + col) * 40 + quad * 8);
#pragma unroll
            for (int nt = 0; nt < 4; ++nt) {
                half8 b = *(const half8*)(Xs + (nt * 16 + col) * 40 + quad * 8);
                accV[nt] = __builtin_amdgcn_mfma_f32_16x16x32_f16(aW, b, accV[nt], 0, 0, 0);
            }
        }
    }

    if (isQ) {
#pragma unroll
        for (int nt = 0; nt < 4; ++nt) {
            int n = n0 + nt * 16 + col;
            int h = n >> 5, d = n & 31;
            float bias = bq[n] * (SCALE * LOG2E);
#pragma unroll
            for (int r = 0; r < 4; ++r) {
                int mg = m0 + wave * 16 + quad * 4 + r;
                int b = mg >> 12, sidx = mg & 4095;
                qbuf[((long long)(b * 8 + h) * 4096 + sidx) * 32 + d] = f2bf(accA[nt][r] + bias);
            }
        }
    } else {
#pragma unroll
        for (int nt = 0; nt < 4; ++nt) {          // K epilogue
            int n = n0 + nt * 16 + col;
            int h = n >> 5, d = n & 31;
            float bias = bkv[n];
#pragma unroll
            for (int r = 0; r < 4; ++r) {
                int mg = m0 + wave * 16 + quad * 4 + r;
                int b = mg >> 12, sidx = mg & 4095;
                kbuf[((long long)(b * 8 + h) * 4096 + sidx) * 32 + d] = f2bf(accA[nt][r] + bias);
            }
        }
#pragma unroll
        for (int nt = 0; nt < 4; ++nt) {          // V epilogue (transposed)
            int s = m0 + nt * 16 + col;
            int b = s >> 12, sidx = s & 4095;
#pragma unroll
            for (int r = 0; r < 4; ++r) {
                int dcol = n0 + wave * 16 + quad * 4 + r;
                int h = dcol >> 5, dd = dcol & 31;
                float bias = bkv[256 + dcol];
                vTb[((long long)((b * 8 + h) * 32 + dd)) * 4096 + sidx] = f2bf(accV[nt][r] + bias);
            }
        }
    }
}

// ------------------------------------------------------------ K2: flash MFMA
// VERBATIM R11/R12 (64.8us). grid 2048 = ks(4) x bh(16) x qb(32); block 256.
__global__ __launch_bounds__(256) void flash_mfma(
    const unsigned short* __restrict__ qbuf,
    const unsigned short* __restrict__ kbuf,
    const unsigned short* __restrict__ vT,
    unsigned short* __restrict__ xpart, float* __restrict__ lpart)
{
    __shared__ unsigned short Ks[128 * 40];
    __shared__ unsigned short Vt[32 * 152];
    __shared__ unsigned short Pb[8][640];

    const int t = threadIdx.x;
    const int wave = t >> 6, lane = t & 63;
    const int col = lane & 15, quad = lane >> 4;
    const int qb = blockIdx.x & 31;
    const int bh = (blockIdx.x >> 5) & 15;
    const int ks = blockIdx.x >> 9;          // 0..3
    const int q0 = qb * 128 + wave * 32;
    const long long kvbase = (long long)bh * 4096 * 32;
    unsigned short* pb0 = Pb[wave * 2];
    unsigned short* pb1 = Pb[wave * 2 + 1];

    const short8 qf0 = *(const short8*)(qbuf + kvbase + (long long)(q0 + col) * 32 + quad * 8);
    const short8 qf1 = *(const short8*)(qbuf + kvbase + (long long)(q0 + 16 + col) * 32 + quad * 8);

    const f32x4 zero = {0.f, 0.f, 0.f, 0.f};
    f32x4 o00 = zero, o01 = zero, o10 = zero, o11 = zero;
    float l0 = 0.f, l1 = 0.f;

    const int krow = t >> 2, kpart = (t & 3) * 8;
    const int vrow = t >> 4, vpart = (t & 15) * 8;

    for (int kt0 = 0; kt0 < 8; ++kt0) {
        const int kt = ks * 8 + kt0;
        uint4 kg0 = *(const uint4*)(kbuf + kvbase + (long long)(kt * 128 + krow) * 32 + kpart);
        uint4 kg1 = *(const uint4*)(kbuf + kvbase + (long long)(kt * 128 + krow + 64) * 32 + kpart);
        uint4 vg0 = *(const uint4*)(vT + ((long long)(bh * 32 + vrow)) * 4096 + kt * 128 + vpart);
        uint4 vg1 = *(const uint4*)(vT + ((long long)(bh * 32 + vrow + 16)) * 4096 + kt * 128 + vpart);
        __syncthreads();
        *(uint4*)(Ks + krow * 40 + kpart) = kg0;
        *(uint4*)(Ks + (krow + 64) * 40 + kpart) = kg1;
        *(uint4*)(Vt + vrow * 152 + vpart) = vg0;
        *(uint4*)(Vt + (vrow + 16) * 152 + vpart) = vg1;
        __syncthreads();

#pragma unroll
        for (int sb = 0; sb < 4; ++sb) {
            const int kb = sb * 32;
            short8 a0 = *(const short8*)(Ks + (kb + col) * 40 + quad * 8);
            short8 a1 = *(const short8*)(Ks + (kb + 16 + col) * 40 + quad * 8);
            short8 v0 = *(const short8*)(Vt + col * 152 + kb + quad * 8);
            short8 v1 = *(const short8*)(Vt + (16 + col) * 152 + kb + quad * 8);
            // ---- q-tile 0
            {
                f32x4 c0 = __builtin_amdgcn_mfma_f32_16x16x32_bf16(a0, qf0, zero, 0, 0, 0);
                f32x4 c1 = __builtin_amdgcn_mfma_f32_16x16x32_bf16(a1, qf0, zero, 0, 0, 0);
                float p0 = fexp2(c0[0]), p1 = fexp2(c0[1]), p2 = fexp2(c0[2]), p3 = fexp2(c0[3]);
                float p4 = fexp2(c1[0]), p5 = fexp2(c1[1]), p6 = fexp2(c1[2]), p7 = fexp2(c1[3]);
                l0 += ((p0 + p1) + (p2 + p3)) + ((p4 + p5) + (p6 + p7));
                uint2 w0 = make_uint2(pk_bf16(p0, p1), pk_bf16(p2, p3));
                uint2 w1 = make_uint2(pk_bf16(p4, p5), pk_bf16(p6, p7));
                *(uint2*)(pb0 + col * 40 + quad * 4) = w0;
                *(uint2*)(pb0 + col * 40 + 16 + quad * 4) = w1;
                short8 pf = *(const short8*)(pb0 + col * 40 + quad * 8);
                o00 = __builtin_amdgcn_mfma_f32_16x16x32_bf16(v0, pf, o00, 0, 0, 0);
                o01 = __builtin_amdgcn_mfma_f32_16x16x32_bf16(v1, pf, o01, 0, 0, 0);
            }
            // ---- q-tile 1 (reuse a0,a1,v0,v1)
            {
                f32x4 c0 = __builtin_amdgcn_mfma_f32_16x16x32_bf16(a0, qf1, zero, 0, 0, 0);
                f32x4 c1 = __builtin_amdgcn_mfma_f32_16x16x32_bf16(a1, qf1, zero, 0, 0, 0);
                float p0 = fexp2(c0[0]), p1 = fexp2(c0[1]), p2 = fexp2(c0[2]), p3 = fexp2(c0[3]);
                float p4 = fexp2(c1[0]), p5 = fexp2(c1[1]), p6 = fexp2(c1[2]), p7 = fexp2(c1[3]);
                l1 += ((p0 + p1) + (p2 + p3)) + ((p4 + p5) + (p6 + p7));
                uint2 w0 = make_uint2(pk_bf16(p0, p1), pk_bf16(p2, p3));
                uint2 w1 = make_uint2(pk_bf16(p4, p5), pk_bf16(p6, p7));
                *(uint2*)(pb1 + col * 40 + quad * 4) = w0;
                *(uint2*)(pb1 + col * 40 + 16 + quad * 4) = w1;
                short8 pf = *(const short8*)(pb1 + col * 40 + quad * 8);
                o10 = __builtin_amdgcn_mfma_f32_16x16x32_bf16(v0, pf, o10, 0, 0, 0);
                o11 = __builtin_amdgcn_mfma_f32_16x16x32_bf16(v1, pf, o11, 0, 0, 0);
            }
        }
    }

    l0 += __shfl_xor(l0, 16, 64); l0 += __shfl_xor(l0, 32, 64);
    l1 += __shfl_xor(l1, 16, 64); l1 += __shfl_xor(l1, 32, 64);

    const int b = bh >> 3, hh = bh & 7;
    unsigned short* xp = xpart + (long long)ks * 2097152;
    {
        unsigned short* rp = xp + ((long long)(b * 4096 + q0 + col)) * 256 + hh * 32;
        union { unsigned short s[4]; uint2 u; } pa, pb2;
#pragma unroll
        for (int r = 0; r < 4; ++r) { pa.s[r] = f2h(o00[r]); pb2.s[r] = f2h(o01[r]); }
        *(uint2*)(rp + quad * 4) = pa.u;
        *(uint2*)(rp + 16 + quad * 4) = pb2.u;
    }
    {
        unsigned short* rp = xp + ((long long)(b * 4096 + q0 + 16 + col)) * 256 + hh * 32;
        union { unsigned short s[4]; uint2 u; } pa, pb2;
#pragma unroll
        for (int r = 0; r < 4; ++r) { pa.s[r] = f2h(o10[r]); pb2.s[r] = f2h(o11[r]); }
        *(uint2*)(rp + quad * 4) = pa.u;
        *(uint2*)(rp + 16 + quad * 4) = pb2.u;
    }

    if (quad == 0)      lpart[ks * 65536 + bh * 4096 + q0 + col] = l0;
    else if (quad == 1) lpart[ks * 65536 + bh * 4096 + q0 + 16 + col] = l1;
}

// ------- K3: combine 4 fp16 partials + 1/l + out-proj (VERBATIM R12)
// grid (128, 4), block 256.
__global__ __launch_bounds__(256) void gemm_outp(
    const unsigned short* __restrict__ xpart, const float* __restrict__ lpart,
    const unsigned short* __restrict__ wfp,
    const float* __restrict__ bp, float* __restrict__ out)
{
    __shared__ unsigned short XsH[64 * 40], XsL[64 * 40], Ws[64 * 40];

    const int t = threadIdx.x, wave = t >> 6, lane = t & 63;
    const int col = lane & 15, quad = lane >> 4;
    const int n0 = blockIdx.y * 64;
    const int m0 = blockIdx.x * 64;
    const int wrow0 = 768 + n0;
    const int srow = t >> 2, spart = (t & 3) * 8;
    const int r = m0 + srow;
    const int bidx = r >> 12, s = r & 4095;

    const f32x4 zero = {0.f, 0.f, 0.f, 0.f};
    f32x4 acc[4] = {zero, zero, zero, zero};

    for (int kt = 0; kt < 8; ++kt) {
        const int k0 = kt * 32;
        float lsum = lpart[(bidx * 8 + kt) * 4096 + s]
                   + lpart[65536 + (bidx * 8 + kt) * 4096 + s]
                   + lpart[131072 + (bidx * 8 + kt) * 4096 + s]
                   + lpart[196608 + (bidx * 8 + kt) * 4096 + s];
        const float linv = 1.f / lsum;

        union { unsigned short s4[8]; uint4 u; } p[4];
#pragma unroll
        for (int ss = 0; ss < 4; ++ss)
            p[ss].u = *(const uint4*)&xpart[(long long)ss * 2097152 +
                                            (long long)r * 256 + k0 + spart];
        union { unsigned short s4[8]; uint4 u; } ph, pl;
#pragma unroll
        for (int j = 0; j < 8; ++j) {
            float xv = (h2f(p[0].s4[j]) + h2f(p[1].s4[j]) +
                        h2f(p[2].s4[j]) + h2f(p[3].s4[j])) * linv;
            unsigned short h = f2h(xv);
            ph.s4[j] = h;
            pl.s4[j] = f2h(xv - h2f(h));
        }
        uint4 wh = *(const uint4*)&wfp[(long long)(wrow0 + srow) * 256 + k0 + spart];
        __syncthreads();
        *(uint4*)&XsH[srow * 40 + spart] = ph.u;
        *(uint4*)&XsL[srow * 40 + spart] = pl.u;
        *(uint4*)&Ws[srow * 40 + spart] = wh;
        __syncthreads();

        half8 a_h = *(const half8*)(XsH + (wave * 16 + col) * 40 + quad * 8);
        half8 a_l = *(const half8*)(XsL + (wave * 16 + col) * 40 + quad * 8);
#pragma unroll
        for (int nt = 0; nt < 4; ++nt) {
            half8 b = *(const half8*)(Ws + (nt * 16 + col) * 40 + quad * 8);
            acc[nt] = __builtin_amdgcn_mfma_f32_16x16x32_f16(a_h, b, acc[nt], 0, 0, 0);
            acc[nt] = __builtin_amdgcn_mfma_f32_16x16x32_f16(a_l, b, acc[nt], 0, 0, 0);
        }
    }

#pragma unroll
    for (int nt = 0; nt < 4; ++nt) {
        int n = n0 + nt * 16 + col;
        float bias = bp[n];
#pragma unroll
        for (int rr = 0; rr < 4; ++rr) {
            int mg = m0 + wave * 16 + quad * 4 + rr;
            out[(long long)mg * 256 + n] = acc[nt][rr] + bias;
        }
    }
}

extern "C" void kernel_launch(void* const* d_in, const int* in_sizes, int n_in,
                              void* d_out, int out_size, void* d_ws, size_t ws_size,
                              hipStream_t stream) {
    const float* query = (const float*)d_in[0];
    const float* sim   = (const float*)d_in[1];
    const float* Wq    = (const float*)d_in[2];
    const float* bq    = (const float*)d_in[3];
    const float* Wkv   = (const float*)d_in[4];
    const float* bkv   = (const float*)d_in[5];
    const float* Wp    = (const float*)d_in[6];
    const float* bp    = (const float*)d_in[7];
    float* out = (float*)d_out;

    unsigned short* wsb = (unsigned short*)d_ws;
    unsigned short* qbuf = wsb;                        // 2,097,152 shorts
    unsigned short* kbuf = wsb + 2097152;
    unsigned short* vT   = wsb + 4194304;              // ends 6,291,456
    unsigned short* wfp  = wsb + 6291456;              // 262,144 fp16
    unsigned short* xpart = wsb + 6553600;             // 4 x 2,097,152 fp16
    float* lpart = (float*)(wsb + 14942208);           // 4 x 65,536 fp32

    prep      <<<dim3(64),     256, 0, stream>>>(Wq, Wkv, Wp, wfp);
    gemm_qkv  <<<dim3(128, 8), 256, 0, stream>>>(query, sim, wfp, bq, bkv,
                                                 qbuf, kbuf, vT);
    flash_mfma<<<dim3(2048),   256, 0, stream>>>(qbuf, kbuf, vT, xpart, lpart);
    gemm_outp <<<dim3(128, 4), 256, 0, stream>>>(xpart, lpart, wfp, bp, out);
}